// Round 15
// baseline (19.222 us; speedup 1.0000x reference)
//
#include <hip/hip_runtime.h>

// out[b,o] = min_i max(x[b,i], w[i,o])  — hard min via bucket-sorted
// early-exit scan (exact-to-fp16: w pre-rounded to fp16, error <= 2^-12
// = 2.44e-4 << 3.36e-3 threshold; x stays fp32).
//
// R15 = R14 structure + fp16 w gather (halves every byte/line-fill term in
// the phase-B bound identified by R9's warm-repeat measurement).
//  K0 conv_w: w fp32 -> fp16 into d_ws (streaming, 512 blocks).
//  K1 fused: phase A = 64-bin counting sort of x row (4 barriers, 1-wave
//     shfl prefix scan); phase B = register-broadcast scan: entries 0..127
//     in one uint4/lane, compile-time v_readlane broadcast; 64 straight-line
//     ushort gathers (128B/wave-instr); per-8 checked tail (exit bound =
//     next entry's bucket lower bound on sorted x — exact); LDS fallback.

#define B_DIM 512
#define I_DIM 512
#define O_DIM 1024
#define NBUCK 64

#define RL(v_, l_) ((unsigned)__builtin_amdgcn_readlane((int)(v_), (l_)))
#define RFL(v_) ((unsigned)__builtin_amdgcn_readfirstlane((int)(v_)))

typedef _Float16 half4v __attribute__((ext_vector_type(4)));

// ---------------- K0: w -> fp16 (streaming) ----------------
__global__ __launch_bounds__(256) void conv_w(
    const float* __restrict__ w, _Float16* __restrict__ wh) {
  const int i = (blockIdx.x * 256 + threadIdx.x) * 4;
  const float4 v = *reinterpret_cast<const float4*>(w + i);
  half4v h;
  h.x = (_Float16)v.x; h.y = (_Float16)v.y;
  h.z = (_Float16)v.z; h.w = (_Float16)v.w;
  *reinterpret_cast<half4v*>(wh + i) = h;
}

// ---------------- K1: fused sort + fp16 gather scan ----------------
__global__ __launch_bounds__(256, 8) void SmoothSTEMinMax_fused(
    const float* __restrict__ x,         // [B, I] fp32
    const _Float16* __restrict__ wh,     // [I, O] fp16
    float* __restrict__ out) {           // [B, O] fp32
  __shared__ unsigned int hist[NBUCK];
  __shared__ uint2 sdat[I_DIM];      // {w-row byte offset (fp16), x valbits}

  const int t = threadIdx.x;
  const int bid = blockIdx.x;
  const int sl = bid & 3;            // o-slice (XCD-pinned via bid%8 round-robin)
  const int b = bid >> 2;            // row
  const int lane = t & 63;

  // ---- Phase A: 64-bin counting sort (4 barriers, 1-wave prefix scan) ----
  const float xv0 = x[b * I_DIM + t];
  const float xv1 = x[b * I_DIM + 256 + t];
  int b0 = (int)(xv0 * 64.0f); b0 = b0 > 63 ? 63 : (b0 < 0 ? 0 : b0);
  int b1 = (int)(xv1 * 64.0f); b1 = b1 > 63 ? 63 : (b1 < 0 ? 0 : b1);

  if (t < NBUCK) hist[t] = 0;
  __syncthreads();
  atomicAdd(&hist[b0], 1u);
  atomicAdd(&hist[b1], 1u);
  __syncthreads();
  if (t < NBUCK) {                   // wave 0 only: shfl inclusive scan
    const unsigned cnt = hist[t];
    unsigned v = cnt;
#pragma unroll
    for (int d = 1; d < 64; d <<= 1) {
      const unsigned n = __shfl_up(v, d, 64);
      if (lane >= d) v += n;
    }
    hist[t] = v - cnt;               // exclusive base -> bucket cursor
  }
  __syncthreads();
  {
    const unsigned p0 = atomicAdd(&hist[b0], 1u);
    sdat[p0] = make_uint2((unsigned)t * (unsigned)(O_DIM * 2), __float_as_uint(xv0));
    const unsigned p1 = atomicAdd(&hist[b1], 1u);
    sdat[p1] = make_uint2((unsigned)(t + 256) * (unsigned)(O_DIM * 2),
                          __float_as_uint(xv1));
  }
  __syncthreads();

  // ---- Phase B: register-broadcast early-exit fp16 gather scan ----
  const unsigned o2 = (unsigned)(sl * 256 + t) * 2u;  // fp16 byte offset in row
  const char* whb = reinterpret_cast<const char*>(wh);
  float A = 3.402823466e+38f;

  // entries 0..127: lane l holds entries 2l (q.x=off,q.y=val), 2l+1 (q.z,q.w)
  const uint4 q = *reinterpret_cast<const uint4*>(&sdat[2 * lane]);

  // straight-line first 64 entries: zero checks, full global-load ILP
#pragma unroll
  for (int c = 0; c < 8; ++c) {
    float wv[8], xv[8];
#pragma unroll
    for (int e = 0; e < 8; ++e) {
      const int g = c * 8 + e;
      const unsigned off = RL((g & 1) ? q.z : q.x, g >> 1);
      const unsigned xb  = RL((g & 1) ? q.w : q.y, g >> 1);
      xv[e] = __uint_as_float(xb);
      wv[e] = (float)*reinterpret_cast<const _Float16*>(whb + (off + o2));
    }
#pragma unroll
    for (int e = 0; e < 8; ++e) A = fminf(A, fmaxf(xv[e], wv[e]));
  }

  int k = 64;
  // register-resident adaptive tail: entries 64..127, exit check per 8
#pragma unroll
  for (int c = 8; c < 16; ++c) {
    const float nx = __uint_as_float(RL(q.y, 4 * c));        // value of entry 8c
    const float th = (float)(int)(nx * 64.0f) * 0.015625f;   // bucket lower bound
    if (!__any(A > th)) break;                               // exact early exit
#pragma unroll
    for (int e = 0; e < 8; ++e) {
      const int g = c * 8 + e;
      const unsigned off = RL((g & 1) ? q.z : q.x, g >> 1);
      const unsigned xb  = RL((g & 1) ? q.w : q.y, g >> 1);
      const float wvv = (float)*reinterpret_cast<const _Float16*>(whb + (off + o2));
      A = fminf(A, fmaxf(__uint_as_float(xb), wvv));
    }
    k += 8;
  }

  // LDS fallback: entries 128..511 (probability ~0; correctness only)
  if (k >= 128) {
    while (k < I_DIM) {
      const float nx = __uint_as_float(RFL(sdat[k].y));
      const float th = (float)(int)(nx * 64.0f) * 0.015625f;
      if (!__any(A > th)) break;
#pragma unroll
      for (int u = 0; u < 8; ++u) {
        const unsigned off = RFL(sdat[k + u].x);
        const unsigned xb  = RFL(sdat[k + u].y);
        const float wvv = (float)*reinterpret_cast<const _Float16*>(whb + (off + o2));
        A = fminf(A, fmaxf(__uint_as_float(xb), wvv));
      }
      k += 8;
    }
  }

  out[b * O_DIM + sl * 256 + t] = A;
}

// ---------------- fp32 fallback (ws too small; not expected) ----------------
__global__ __launch_bounds__(256) void brute_simple(
    const float* __restrict__ x, const float* __restrict__ w,
    float* __restrict__ out) {
  const int o = blockIdx.y * 256 + threadIdx.x;
  const int b = blockIdx.x;
  float A = 3.402823466e+38f;
  for (int i = 0; i < I_DIM; ++i)
    A = fminf(A, fmaxf(x[b * I_DIM + i], w[i * O_DIM + o]));
  out[b * O_DIM + o] = A;
}

extern "C" void kernel_launch(void* const* d_in, const int* in_sizes, int n_in,
                              void* d_out, int out_size, void* d_ws, size_t ws_size,
                              hipStream_t stream) {
  const float* x = (const float*)d_in[0];   // [512, 512]
  const float* w = (const float*)d_in[1];   // [512, 1024]
  float* out = (float*)d_out;               // [512, 1024]

  const size_t wh_bytes = (size_t)I_DIM * O_DIM * sizeof(_Float16);  // 1 MB
  if (ws_size >= wh_bytes) {
    _Float16* wh = (_Float16*)d_ws;
    conv_w<<<(I_DIM * O_DIM) / (256 * 4), 256, 0, stream>>>(w, wh);
    // 1D grid: bid%8 = XCD; slice = bid&3, row = bid>>2 (XCD-pinned w slices)
    SmoothSTEMinMax_fused<<<B_DIM * 4, 256, 0, stream>>>(x, wh, out);
  } else {
    dim3 grid(B_DIM, O_DIM / 256);
    brute_simple<<<grid, 256, 0, stream>>>(x, w, out);
  }
}